// Round 13
// baseline (200.451 us; speedup 1.0000x reference)
//
#include <hip/hip_runtime.h>
#include <cmath>

// Problem geometry (fixed by the reference): 128 images of 512x512 f32.
static constexpr int IMH = 512;
static constexpr int IMW = 512;
static constexpr int IMG_PIX = IMH * IMW;

struct Weights {
    float kx[7];
    float ky[13];
};

__global__ void init_minmax_kernel(int* __restrict__ mm, int nimg) {
    int i = blockIdx.x * blockDim.x + threadIdx.x;
    if (i < nimg) {
        mm[2 * i]     = 0x7f7fffff;  // +FLT_MAX bits (min accumulator)
        mm[2 * i + 1] = 0;           // 0.0f bits (max accumulator; blur > 0)
    }
}

// DPP whole-wave shift, VALU-speed cross-lane. 0x130 = wave_shl:1
// (out[i] = in[i-1], out[0] = 0), 0x138 = wave_shr:1 (out[i] = in[i+1],
// out[63] = 0). bound_ctrl=1 zeroes edge lanes.
template <int CTRL>
__device__ __forceinline__ float gm_dpp(float v) {
    return __int_as_float(__builtin_amdgcn_update_dpp(
        0, __float_as_int(v), CTRL, 0xF, 0xF, true));
}

// Column-sweep fused kernel: zero LDS, zero barriers, zero bank conflicts.
// Block = 384 threads = 6 waves = ONE band's 6 row-chunks (block<->band store
// layout -- the configuration measured clean at ~131 MB WRITE_SIZE in
// r7/r10/r12; r11's flat wave<->band mapping amplified writes to 287 MB).
// Grid 10 bands x 128 images = 1280 blocks = 7680 waves = 93.75% of the
// 8192 wave slots in ONE residency round (5 blocks/CU = 30 waves/CU <= 32).
// Chunks: q=0..4 -> 86 output rows, q=5 -> 82 (r11's verified geometry).
// Per row: grad via register history + 2 DPP shifts, blurX via 6 DPP shifts,
// blurY via a 13-register ring with static indexing; 4-row-deep load
// pipeline. Reflect padding folded into the LOAD column of halo lanes
// (left/right swap vanishes under squaring -> bit-identical values).
// FP contraction off (mul-then-add order) -- matches reference bit-exactly.
__global__ __launch_bounds__(384, 7) void blur_kernel(
        const float* __restrict__ in, float* __restrict__ blur,
        int* __restrict__ mm, Weights wt) {
#pragma clang fp contract(off)
    const int band = blockIdx.x;                   // 0..9
    const int img  = blockIdx.y;                   // 0..127
    const int q    = threadIdx.x >> 6;             // row chunk 0..5
    const int lane = threadIdx.x & 63;
    const int cb   = band * 56 - 4;                // wave covers cols cb..cb+63
    const int c    = cb + lane;
    // Load column: reflect out-of-image halo columns (grad commutes with
    // reflection up to a sign that squaring erases).
    int lc = c < 0 ? -c : (c > IMW - 1 ? 2 * (IMW - 1) - c : c);
    const bool cvalid = (lane >= 4) && (lane <= 59) && (c <= IMW - 1);
    const bool has_l  = (lc >= 1);                 // zero-pad guard at image edge
    const bool has_r  = (lc <= IMW - 2);

    const float* __restrict__ ip = in + (size_t)img * IMG_PIX;
    float* __restrict__ bp = blur + (size_t)img * IMG_PIX;

    // Chunk geometry (outputs): [86q, 86q+86) for q<5, [430,512) for q=5.
    const int gr0       = (q == 0) ? 0 : 86 * q - 6;   // first sweep row
    const int M         = (q == 5) ? 5 : 6;            // main-loop iters
    const int tail_n    = (q == 0) ? 1 : ((q == 5) ? 10 : 7);
    const int tail_base = gr0 + 13 + 13 * M;           // first tail grad row

    // x register pipeline: rows gr-1..gr+3, prefetch gr+4, moving pointers.
    const float* xp = ip + (size_t)gr0 * IMW + lc;
    float x_m1 = (q == 0) ? 0.0f : xp[-IMW];
    float x_0  = xp[0];
    float x_p1 = xp[IMW];
    float x_p2 = xp[2 * (size_t)IMW];
    float x_p3 = xp[3 * (size_t)IMW];
    const float* xp_pref = xp + 4 * (size_t)IMW;   // row gr0+4
    float* op = bp + (size_t)(gr0 + 6) * IMW + c;  // first regular orow

    float w[13];                                    // bx ring, static idx
    float tmn = 3.402823466e38f;
    float tmx = 0.0f;

#define GM_ROW(S, DO_OUT, DN, PREF)                                            \
    {                                                                          \
        float x_pf = (PREF);                                                   \
        float xl_ = gm_dpp<0x130>(x_0);      /* x[col-1] */                    \
        float xr_ = gm_dpp<0x138>(x_0);      /* x[col+1] */                    \
        float lf_ = has_l ? xl_ : 0.0f;                                        \
        float rt_ = has_r ? xr_ : 0.0f;                                        \
        float gv_ = (DN) - x_m1;                                               \
        float gh_ = rt_ - lf_;                                                 \
        float sg_ = gv_ * gv_ + gh_ * gh_;   /* contract(off): mul,mul,add */  \
        sg_ = sg_ + 1e-6f;                                                     \
        float g_ = sqrtf(sg_);                                                 \
        float gm1_ = gm_dpp<0x130>(g_);                                        \
        float gm2_ = gm_dpp<0x130>(gm1_);                                      \
        float gm3_ = gm_dpp<0x130>(gm2_);                                      \
        float gp1_ = gm_dpp<0x138>(g_);                                        \
        float gp2_ = gm_dpp<0x138>(gp1_);                                      \
        float gp3_ = gm_dpp<0x138>(gp2_);                                      \
        float ax_ = 0.0f;                                                      \
        ax_ += wt.kx[0] * gm3_;                                                \
        ax_ += wt.kx[1] * gm2_;                                                \
        ax_ += wt.kx[2] * gm1_;                                                \
        ax_ += wt.kx[3] * g_;                                                  \
        ax_ += wt.kx[4] * gp1_;                                                \
        ax_ += wt.kx[5] * gp2_;                                                \
        ax_ += wt.kx[6] * gp3_;                                                \
        w[(S) % 13] = ax_;                                                     \
        if (DO_OUT) {                                                          \
            float ay_ = 0.0f;                                                  \
            ay_ += wt.ky[0]  * w[((S) + 1)  % 13];                             \
            ay_ += wt.ky[1]  * w[((S) + 2)  % 13];                             \
            ay_ += wt.ky[2]  * w[((S) + 3)  % 13];                             \
            ay_ += wt.ky[3]  * w[((S) + 4)  % 13];                             \
            ay_ += wt.ky[4]  * w[((S) + 5)  % 13];                             \
            ay_ += wt.ky[5]  * w[((S) + 6)  % 13];                             \
            ay_ += wt.ky[6]  * w[((S) + 7)  % 13];                             \
            ay_ += wt.ky[7]  * w[((S) + 8)  % 13];                             \
            ay_ += wt.ky[8]  * w[((S) + 9)  % 13];                             \
            ay_ += wt.ky[9]  * w[((S) + 10) % 13];                             \
            ay_ += wt.ky[10] * w[((S) + 11) % 13];                             \
            ay_ += wt.ky[11] * w[((S) + 12) % 13];                             \
            ay_ += wt.ky[12] * w[((S) + 13) % 13];                             \
            if (cvalid) {                                                      \
                *op = ay_;                                                     \
                tmn = fminf(tmn, ay_);                                         \
                tmx = fmaxf(tmx, ay_);                                         \
            }                                                                  \
            op += IMW;                                                         \
        }                                                                      \
        x_m1 = x_0; x_0 = x_p1; x_p1 = x_p2; x_p2 = x_p3; x_p3 = x_pf;         \
        xp_pref += IMW;                                                        \
    }

    // ---- peel: ring fill, rows gr0..gr0+12 (one output at s=12) ----
    // Prefetch rows gr0+4..gr0+16 -- always in-image (max 440 at q=5).
    GM_ROW(0,  false, x_p1, xp_pref[0])
    GM_ROW(1,  false, x_p1, xp_pref[0])
    GM_ROW(2,  false, x_p1, xp_pref[0])
    GM_ROW(3,  false, x_p1, xp_pref[0])
    GM_ROW(4,  false, x_p1, xp_pref[0])
    GM_ROW(5,  false, x_p1, xp_pref[0])
    GM_ROW(6,  false, x_p1, xp_pref[0])
    GM_ROW(7,  false, x_p1, xp_pref[0])
    GM_ROW(8,  false, x_p1, xp_pref[0])
    GM_ROW(9,  false, x_p1, xp_pref[0])
    GM_ROW(10, false, x_p1, xp_pref[0])
    GM_ROW(11, false, x_p1, xp_pref[0])
    GM_ROW(12, true,  x_p1, xp_pref[0])

    // ---- top reflected outputs (q==0: rows 0..5 from ring rows 0..11) ----
    if (q == 0) {
        #pragma unroll
        for (int orow = 0; orow < 6; ++orow) {
            float ay = 0.0f;
            #pragma unroll
            for (int j = 0; j < 13; ++j) {
                int t = orow + j - 6;
                t = t < 0 ? -t : t;              // compile-time per (orow,j)
                ay += wt.ky[j] * w[t];           // slot == row for q==0
            }
            if (cvalid) {
                bp[(size_t)orow * IMW + c] = ay;
                tmn = fminf(tmn, ay);
                tmx = fmaxf(tmx, ay);
            }
        }
    }

    // ---- main loop: M iters x 13 rows, fully guard-free ----
    // Max prefetch row = gr0+16+13M <= 505 for every q -- always in-image.
    for (int giter = 0; giter < M; ++giter) {
        GM_ROW(0,  true, x_p1, xp_pref[0])
        GM_ROW(1,  true, x_p1, xp_pref[0])
        GM_ROW(2,  true, x_p1, xp_pref[0])
        GM_ROW(3,  true, x_p1, xp_pref[0])
        GM_ROW(4,  true, x_p1, xp_pref[0])
        GM_ROW(5,  true, x_p1, xp_pref[0])
        GM_ROW(6,  true, x_p1, xp_pref[0])
        GM_ROW(7,  true, x_p1, xp_pref[0])
        GM_ROW(8,  true, x_p1, xp_pref[0])
        GM_ROW(9,  true, x_p1, xp_pref[0])
        GM_ROW(10, true, x_p1, xp_pref[0])
        GM_ROW(11, true, x_p1, xp_pref[0])
        GM_ROW(12, true, x_p1, xp_pref[0])
    }

    // ---- tail: grad rows tail_base..tail_base+tail_n-1, guarded ----
    // Slot of tail row S is S (13+13M ≡ 0 mod 13). Row 511 (q=5, S=9) takes
    // dn=0; prefetch guarded past the image bottom.
#define GM_TAILROW(S)                                                          \
    if ((S) < tail_n) {                                                        \
        GM_ROW(S, true,                                                        \
               ((tail_base + (S)) == IMH - 1) ? 0.0f : x_p1,                   \
               ((tail_base + (S) + 4) <= IMH - 1) ? xp_pref[0] : 0.0f)         \
    }
    GM_TAILROW(0)
    GM_TAILROW(1)
    GM_TAILROW(2)
    GM_TAILROW(3)
    GM_TAILROW(4)
    GM_TAILROW(5)
    GM_TAILROW(6)
    GM_TAILROW(7)
    GM_TAILROW(8)
    GM_TAILROW(9)
#undef GM_TAILROW
#undef GM_ROW

    // ---- bottom reflected outputs (q==5: rows 506..511) ----
    // gr0 = 424; row t (500..511) sits at slot (t-424)%13 after the sweep.
    if (q == 5) {
        #pragma unroll
        for (int oo = 0; oo < 6; ++oo) {
            int orow = 506 + oo;
            float ay = 0.0f;
            #pragma unroll
            for (int j = 0; j < 13; ++j) {
                int t = orow + j - 6;
                t = t > IMH - 1 ? 2 * (IMH - 1) - t : t;  // compile-time
                ay += wt.ky[j] * w[(t - 424) % 13];
            }
            if (cvalid) {
                bp[(size_t)orow * IMW + c] = ay;
                tmn = fminf(tmn, ay);
                tmx = fmaxf(tmx, ay);
            }
        }
    }

    // ---- per-wave reduce + per-image atomics ----
    #pragma unroll
    for (int off = 32; off > 0; off >>= 1) {
        tmn = fminf(tmn, __shfl_xor(tmn, off));
        tmx = fmaxf(tmx, __shfl_xor(tmx, off));
    }
    if (lane == 0) {
        // blur values strictly positive -> float order == int order
        atomicMin(&mm[2 * img], __float_as_int(tmn));
        atomicMax(&mm[2 * img + 1], __float_as_int(tmx));
    }
}

// Normalize + emit both masks as INT32 0/1 (bool output dtype -> int32).
// blurNe holds blur f32 bit patterns on entry (second half of d_out used as
// scratch); each thread overwrites exactly the elements it read.
__global__ __launch_bounds__(256) void mask_kernel(
        const int* __restrict__ mm, int* __restrict__ edge,
        int* __restrict__ blurNe, long long n4) {
#pragma clang fp contract(off)
    const long long stride = (long long)gridDim.x * blockDim.x;
    for (long long i = (long long)blockIdx.x * blockDim.x + threadIdx.x;
         i < n4; i += stride) {
        int img = (int)(i >> 16);  // 262144/4 = 65536 vec4 per image
        float mn = __int_as_float(mm[2 * img]);
        float mx = __int_as_float(mm[2 * img + 1]);
        float d = mx - mn;
        int4 vi = reinterpret_cast<const int4*>(blurNe)[i];
        float4 v = make_float4(__int_as_float(vi.x), __int_as_float(vi.y),
                               __int_as_float(vi.z), __int_as_float(vi.w));
        // true division to match reference normalization exactly
        float n0 = (v.x - mn) / d;
        float n1 = (v.y - mn) / d;
        float n2 = (v.z - mn) / d;
        float n3 = (v.w - mn) / d;
        int4 e, ne;
        e.x = (n0 < 0.1f) ? 1 : 0;  ne.x = e.x ^ 1;
        e.y = (n1 < 0.1f) ? 1 : 0;  ne.y = e.y ^ 1;
        e.z = (n2 < 0.1f) ? 1 : 0;  ne.z = e.z ^ 1;
        e.w = (n3 < 0.1f) ? 1 : 0;  ne.w = e.w ^ 1;
        reinterpret_cast<int4*>(edge)[i] = e;
        reinterpret_cast<int4*>(blurNe)[i] = ne;
    }
}

extern "C" void kernel_launch(void* const* d_in, const int* in_sizes, int n_in,
                              void* d_out, int out_size, void* d_ws, size_t ws_size,
                              hipStream_t stream) {
    const float* x = (const float*)d_in[0];
    int* out = (int*)d_out;
    const long long N = (long long)in_sizes[0];        // 33554432
    const int nimg = (int)(N / IMG_PIX);               // 128
    float* blur = (float*)(out + N);                   // scratch in 2nd output half
    int* mm = (int*)d_ws;                              // 2 ints per image

    // f32 Gaussian weights, mimicking the jnp float32 ops
    Weights wt;
    {
        float tmp[13];
        float s = 0.0f;
        for (int i = 0; i < 7; ++i) {
            float t = (float)i - 3.0f;
            float u = t / 10.0f;
            tmp[i] = expf(-0.5f * (u * u));
            s += tmp[i];
        }
        for (int i = 0; i < 7; ++i) wt.kx[i] = tmp[i] / s;
        s = 0.0f;
        for (int i = 0; i < 13; ++i) {
            float t = (float)i - 6.0f;
            float u = t / 10.0f;
            tmp[i] = expf(-0.5f * (u * u));
            s += tmp[i];
        }
        for (int i = 0; i < 13; ++i) wt.ky[i] = tmp[i] / s;
    }

    init_minmax_kernel<<<1, 256, 0, stream>>>(mm, nimg);
    blur_kernel<<<dim3(10, nimg), 384, 0, stream>>>(x, blur, mm, wt);
    mask_kernel<<<4096, 256, 0, stream>>>(mm, out, (int*)blur, N / 4);
}

// Round 15
// 163.482 us; speedup vs baseline: 1.2261x; 1.2261x over previous
//
#include <hip/hip_runtime.h>
#include <cmath>

// Problem geometry (fixed by the reference): 128 images of 512x512 f32.
static constexpr int IMH = 512;
static constexpr int IMW = 512;
static constexpr int IMG_PIX = IMH * IMW;

typedef int nt_int4 __attribute__((ext_vector_type(4)));  // native vec for nt store

struct Weights {
    float kx[7];
    float ky[13];
};

__global__ void init_minmax_kernel(int* __restrict__ mm, int nimg) {
    int i = blockIdx.x * blockDim.x + threadIdx.x;
    if (i < nimg) {
        mm[2 * i]     = 0x7f7fffff;  // +FLT_MAX bits (min accumulator)
        mm[2 * i + 1] = 0;           // 0.0f bits (max accumulator; blur > 0)
    }
}

// DPP whole-wave shift, VALU-speed cross-lane. 0x130 = wave_shl:1
// (out[i] = in[i-1], out[0] = 0), 0x138 = wave_shr:1 (out[i] = in[i+1],
// out[63] = 0). bound_ctrl=1 zeroes edge lanes.
template <int CTRL>
__device__ __forceinline__ float gm_dpp(float v) {
    return __int_as_float(__builtin_amdgcn_update_dpp(
        0, __float_as_int(v), CTRL, 0xF, 0xF, true));
}

// Column-sweep fused kernel: zero LDS, zero barriers, zero bank conflicts.
// Block = 320 threads = 5 waves = ONE band's 5 row-chunks (block<->band store
// layout -- measured clean at ~131 MB WRITE_SIZE; the r11 flat mapping
// amplified writes to 287 MB). Grid 10 bands x 128 images = 1280 blocks =
// 6400 waves (the best-measured residency config, r12 = 192.9 us total).
// Chunks: q0:103, q1:103, q2:102, q3:102, q4:102 output rows. Per row: grad
// via register history + 2 DPP shifts, blurX via 6 DPP shifts, blurY via a
// 13-register ring with static indexing. 6-row-deep load pipeline (~750
// issue-cycles of latency cover, above L3-hit latency); q4 runs main M=6 so
// the guard-free main loop never prefetches past row 511 (tail = 17 guarded
// rows). Reflect padding folded into the LOAD column of halo lanes
// (left/right swap vanishes under squaring -> bit-identical values).
// FP contraction off (mul-then-add order) -- matches reference bit-exactly.
__global__ __launch_bounds__(320, 6) void blur_kernel(
        const float* __restrict__ in, float* __restrict__ blur,
        int* __restrict__ mm, Weights wt) {
#pragma clang fp contract(off)
    const int band = blockIdx.x;                   // 0..9
    const int img  = blockIdx.y;                   // 0..127
    const int q    = threadIdx.x >> 6;             // row chunk 0..4
    const int lane = threadIdx.x & 63;
    const int cb   = band * 56 - 4;                // wave covers cols cb..cb+63
    const int c    = cb + lane;
    // Load column: reflect out-of-image halo columns (grad commutes with
    // reflection up to a sign that squaring erases).
    int lc = c < 0 ? -c : (c > IMW - 1 ? 2 * (IMW - 1) - c : c);
    const bool cvalid = (lane >= 4) && (lane <= 59) && (c <= IMW - 1);
    const bool has_l  = (lc >= 1);                 // zero-pad guard at image edge
    const bool has_r  = (lc <= IMW - 2);

    const float* __restrict__ ip = in + (size_t)img * IMG_PIX;
    float* __restrict__ bp = blur + (size_t)img * IMG_PIX;

    // Chunk geometry (outputs): q0: 0..102, q1: 103..205, q2: 206..307,
    // q3: 308..409, q4: 410..511. First sweep (grad) row:
    const int gr0 = (q == 0) ? 0 : ((q == 1) ? 97 : ((q == 2) ? 200
                   : ((q == 3) ? 302 : 404)));
    // Sweep = 13 peel + 13*M main + tail_n tail rows.
    const int M         = (q == 4) ? 6 : 7;
    const int tail_n    = (q == 0) ? 5 : ((q == 1) ? 11 : ((q == 4) ? 17 : 10));
    const int tail_base = gr0 + 13 + 13 * M;       // 104 or 91 past gr0; %13==0

    // x register pipeline: rows gr-1..gr+5, prefetch gr+6, moving pointers.
    const float* xp = ip + (size_t)gr0 * IMW + lc;
    float x_m1 = (q == 0) ? 0.0f : xp[-IMW];
    float x_0  = xp[0];
    float x_p1 = xp[IMW];
    float x_p2 = xp[2 * (size_t)IMW];
    float x_p3 = xp[3 * (size_t)IMW];
    float x_p4 = xp[4 * (size_t)IMW];
    float x_p5 = xp[5 * (size_t)IMW];
    const float* xp_pref = xp + 6 * (size_t)IMW;   // row gr0+6
    float* op = bp + (size_t)(gr0 + 6) * IMW + c;  // first regular orow

    float w[13];                                    // bx ring, static idx
    float tmn = 3.402823466e38f;
    float tmx = 0.0f;

#define GM_ROW(S, DO_OUT, DN, PREF)                                            \
    {                                                                          \
        float x_pf = (PREF);                                                   \
        float xl_ = gm_dpp<0x130>(x_0);      /* x[col-1] */                    \
        float xr_ = gm_dpp<0x138>(x_0);      /* x[col+1] */                    \
        float lf_ = has_l ? xl_ : 0.0f;                                        \
        float rt_ = has_r ? xr_ : 0.0f;                                        \
        float gv_ = (DN) - x_m1;                                               \
        float gh_ = rt_ - lf_;                                                 \
        float sg_ = gv_ * gv_ + gh_ * gh_;   /* contract(off): mul,mul,add */  \
        sg_ = sg_ + 1e-6f;                                                     \
        float g_ = sqrtf(sg_);                                                 \
        float gm1_ = gm_dpp<0x130>(g_);                                        \
        float gm2_ = gm_dpp<0x130>(gm1_);                                      \
        float gm3_ = gm_dpp<0x130>(gm2_);                                      \
        float gp1_ = gm_dpp<0x138>(g_);                                        \
        float gp2_ = gm_dpp<0x138>(gp1_);                                      \
        float gp3_ = gm_dpp<0x138>(gp2_);                                      \
        float ax_ = 0.0f;                                                      \
        ax_ += wt.kx[0] * gm3_;                                                \
        ax_ += wt.kx[1] * gm2_;                                                \
        ax_ += wt.kx[2] * gm1_;                                                \
        ax_ += wt.kx[3] * g_;                                                  \
        ax_ += wt.kx[4] * gp1_;                                                \
        ax_ += wt.kx[5] * gp2_;                                                \
        ax_ += wt.kx[6] * gp3_;                                                \
        w[(S) % 13] = ax_;                                                     \
        if (DO_OUT) {                                                          \
            float ay_ = 0.0f;                                                  \
            ay_ += wt.ky[0]  * w[((S) + 1)  % 13];                             \
            ay_ += wt.ky[1]  * w[((S) + 2)  % 13];                             \
            ay_ += wt.ky[2]  * w[((S) + 3)  % 13];                             \
            ay_ += wt.ky[3]  * w[((S) + 4)  % 13];                             \
            ay_ += wt.ky[4]  * w[((S) + 5)  % 13];                             \
            ay_ += wt.ky[5]  * w[((S) + 6)  % 13];                             \
            ay_ += wt.ky[6]  * w[((S) + 7)  % 13];                             \
            ay_ += wt.ky[7]  * w[((S) + 8)  % 13];                             \
            ay_ += wt.ky[8]  * w[((S) + 9)  % 13];                             \
            ay_ += wt.ky[9]  * w[((S) + 10) % 13];                             \
            ay_ += wt.ky[10] * w[((S) + 11) % 13];                             \
            ay_ += wt.ky[11] * w[((S) + 12) % 13];                             \
            ay_ += wt.ky[12] * w[((S) + 13) % 13];                             \
            if (cvalid) {                                                      \
                *op = ay_;                                                     \
                tmn = fminf(tmn, ay_);                                         \
                tmx = fmaxf(tmx, ay_);                                         \
            }                                                                  \
            op += IMW;                                                         \
        }                                                                      \
        x_m1 = x_0; x_0 = x_p1; x_p1 = x_p2; x_p2 = x_p3; x_p3 = x_p4;         \
        x_p4 = x_p5; x_p5 = x_pf;                                              \
        xp_pref += IMW;                                                        \
    }

    // ---- peel: ring fill, rows gr0..gr0+12 (one output at s=12) ----
    // Prefetch rows gr0+6..gr0+18 -- always in-image (max 422 at q=4).
    GM_ROW(0,  false, x_p1, xp_pref[0])
    GM_ROW(1,  false, x_p1, xp_pref[0])
    GM_ROW(2,  false, x_p1, xp_pref[0])
    GM_ROW(3,  false, x_p1, xp_pref[0])
    GM_ROW(4,  false, x_p1, xp_pref[0])
    GM_ROW(5,  false, x_p1, xp_pref[0])
    GM_ROW(6,  false, x_p1, xp_pref[0])
    GM_ROW(7,  false, x_p1, xp_pref[0])
    GM_ROW(8,  false, x_p1, xp_pref[0])
    GM_ROW(9,  false, x_p1, xp_pref[0])
    GM_ROW(10, false, x_p1, xp_pref[0])
    GM_ROW(11, false, x_p1, xp_pref[0])
    GM_ROW(12, true,  x_p1, xp_pref[0])

    // ---- top reflected outputs (q==0: rows 0..5 from ring rows 0..11) ----
    if (q == 0) {
        #pragma unroll
        for (int orow = 0; orow < 6; ++orow) {
            float ay = 0.0f;
            #pragma unroll
            for (int j = 0; j < 13; ++j) {
                int t = orow + j - 6;
                t = t < 0 ? -t : t;              // compile-time per (orow,j)
                ay += wt.ky[j] * w[t];           // slot == row for q==0
            }
            if (cvalid) {
                bp[(size_t)orow * IMW + c] = ay;
                tmn = fminf(tmn, ay);
                tmx = fmaxf(tmx, ay);
            }
        }
    }

    // ---- main loop: M iters x 13 rows, fully guard-free ----
    // Max prefetch row = gr0+18+13M: q0..q3 <= 411, q4 = 500 -- in-image.
    for (int giter = 0; giter < M; ++giter) {
        GM_ROW(0,  true, x_p1, xp_pref[0])
        GM_ROW(1,  true, x_p1, xp_pref[0])
        GM_ROW(2,  true, x_p1, xp_pref[0])
        GM_ROW(3,  true, x_p1, xp_pref[0])
        GM_ROW(4,  true, x_p1, xp_pref[0])
        GM_ROW(5,  true, x_p1, xp_pref[0])
        GM_ROW(6,  true, x_p1, xp_pref[0])
        GM_ROW(7,  true, x_p1, xp_pref[0])
        GM_ROW(8,  true, x_p1, xp_pref[0])
        GM_ROW(9,  true, x_p1, xp_pref[0])
        GM_ROW(10, true, x_p1, xp_pref[0])
        GM_ROW(11, true, x_p1, xp_pref[0])
        GM_ROW(12, true, x_p1, xp_pref[0])
    }

    // ---- tail: grad rows tail_base..tail_base+tail_n-1, guarded ----
    // Slot of tail row S is S%13 (tail_base ≡ gr0 mod 13). Row 511 (q=4,
    // S=16) takes dn=0; prefetch guarded past the image bottom.
#define GM_TAILROW(S)                                                          \
    if ((S) < tail_n) {                                                        \
        GM_ROW(S, true,                                                        \
               ((tail_base + (S)) == IMH - 1) ? 0.0f : x_p1,                   \
               ((tail_base + (S) + 6) <= IMH - 1) ? xp_pref[0] : 0.0f)         \
    }
    GM_TAILROW(0)
    GM_TAILROW(1)
    GM_TAILROW(2)
    GM_TAILROW(3)
    GM_TAILROW(4)
    GM_TAILROW(5)
    GM_TAILROW(6)
    GM_TAILROW(7)
    GM_TAILROW(8)
    GM_TAILROW(9)
    GM_TAILROW(10)
    GM_TAILROW(11)
    GM_TAILROW(12)
    GM_TAILROW(13)
    GM_TAILROW(14)
    GM_TAILROW(15)
    GM_TAILROW(16)
#undef GM_TAILROW
#undef GM_ROW

    // ---- bottom reflected outputs (q==4: rows 506..511) ----
    // gr0 = 404; row t (500..511) sits at slot (t-404)%13 after the sweep.
    if (q == 4) {
        #pragma unroll
        for (int oo = 0; oo < 6; ++oo) {
            int orow = 506 + oo;
            float ay = 0.0f;
            #pragma unroll
            for (int j = 0; j < 13; ++j) {
                int t = orow + j - 6;
                t = t > IMH - 1 ? 2 * (IMH - 1) - t : t;  // compile-time
                ay += wt.ky[j] * w[(t - 404) % 13];
            }
            if (cvalid) {
                bp[(size_t)orow * IMW + c] = ay;
                tmn = fminf(tmn, ay);
                tmx = fmaxf(tmx, ay);
            }
        }
    }

    // ---- per-wave reduce + per-image atomics ----
    #pragma unroll
    for (int off = 32; off > 0; off >>= 1) {
        tmn = fminf(tmn, __shfl_xor(tmn, off));
        tmx = fmaxf(tmx, __shfl_xor(tmx, off));
    }
    if (lane == 0) {
        // blur values strictly positive -> float order == int order
        atomicMin(&mm[2 * img], __float_as_int(tmn));
        atomicMax(&mm[2 * img + 1], __float_as_int(tmx));
    }
}

// Normalize + emit both masks as INT32 0/1 (bool output dtype -> int32).
// blurNe holds blur f32 bit patterns on entry (second half of d_out used as
// scratch); each thread overwrites exactly the elements it read.
// Mask stores are NON-TEMPORAL (native ext_vector type for the builtin):
// they are never re-read; bypassing L3 keeps the blur scratch resident so
// mask reads stay L3-hits.
__global__ __launch_bounds__(256) void mask_kernel(
        const int* __restrict__ mm, int* __restrict__ edge,
        int* __restrict__ blurNe, long long n4) {
#pragma clang fp contract(off)
    const long long stride = (long long)gridDim.x * blockDim.x;
    for (long long i = (long long)blockIdx.x * blockDim.x + threadIdx.x;
         i < n4; i += stride) {
        int img = (int)(i >> 16);  // 262144/4 = 65536 vec4 per image
        float mn = __int_as_float(mm[2 * img]);
        float mx = __int_as_float(mm[2 * img + 1]);
        float d = mx - mn;
        nt_int4 vi = *(reinterpret_cast<const nt_int4*>(blurNe) + i);
        // true division to match reference normalization exactly
        float n0 = (__int_as_float(vi.x) - mn) / d;
        float n1 = (__int_as_float(vi.y) - mn) / d;
        float n2 = (__int_as_float(vi.z) - mn) / d;
        float n3 = (__int_as_float(vi.w) - mn) / d;
        nt_int4 e, ne;
        e.x = (n0 < 0.1f) ? 1 : 0;  ne.x = e.x ^ 1;
        e.y = (n1 < 0.1f) ? 1 : 0;  ne.y = e.y ^ 1;
        e.z = (n2 < 0.1f) ? 1 : 0;  ne.z = e.z ^ 1;
        e.w = (n3 < 0.1f) ? 1 : 0;  ne.w = e.w ^ 1;
        __builtin_nontemporal_store(e, reinterpret_cast<nt_int4*>(edge) + i);
        __builtin_nontemporal_store(ne, reinterpret_cast<nt_int4*>(blurNe) + i);
    }
}

extern "C" void kernel_launch(void* const* d_in, const int* in_sizes, int n_in,
                              void* d_out, int out_size, void* d_ws, size_t ws_size,
                              hipStream_t stream) {
    const float* x = (const float*)d_in[0];
    int* out = (int*)d_out;
    const long long N = (long long)in_sizes[0];        // 33554432
    const int nimg = (int)(N / IMG_PIX);               // 128
    float* blur = (float*)(out + N);                   // scratch in 2nd output half
    int* mm = (int*)d_ws;                              // 2 ints per image

    // f32 Gaussian weights, mimicking the jnp float32 ops
    Weights wt;
    {
        float tmp[13];
        float s = 0.0f;
        for (int i = 0; i < 7; ++i) {
            float t = (float)i - 3.0f;
            float u = t / 10.0f;
            tmp[i] = expf(-0.5f * (u * u));
            s += tmp[i];
        }
        for (int i = 0; i < 7; ++i) wt.kx[i] = tmp[i] / s;
        s = 0.0f;
        for (int i = 0; i < 13; ++i) {
            float t = (float)i - 6.0f;
            float u = t / 10.0f;
            tmp[i] = expf(-0.5f * (u * u));
            s += tmp[i];
        }
        for (int i = 0; i < 13; ++i) wt.ky[i] = tmp[i] / s;
    }

    init_minmax_kernel<<<1, 256, 0, stream>>>(mm, nimg);
    blur_kernel<<<dim3(10, nimg), 320, 0, stream>>>(x, blur, mm, wt);
    mask_kernel<<<4096, 256, 0, stream>>>(mm, out, (int*)blur, N / 4);
}